// Round 3
// baseline (795.694 us; speedup 1.0000x reference)
//
#include <hip/hip_runtime.h>

#define NQ 2048
#define NT 131072
#define DD 64
#define MM 1024
#define NBUCK 512          // coarse buckets: v >> 8
#define BCAP 4608          // per-bucket capacity (mean 3906, sigma 62; +11 sigma)
#define CHUNK 4096         // edges per bin block

// Yab[u][0..63] = Xq[u]@Wa ; Yab[u][64..127] = Xq[u]@Wb (interleaved rows: one
// base address per edge in bucket_kernel, both score rows contiguous in L2).
__global__ void yq_kernel(const float* __restrict__ Xq,
                          const float* __restrict__ Wa,
                          const float* __restrict__ Wb,
                          float* __restrict__ Yab) {
    int r = blockIdx.x * 4 + (threadIdx.x >> 6);
    int j = threadIdx.x & 63;
    float sa = 0.f, sb = 0.f;
#pragma unroll
    for (int k = 0; k < DD; ++k) {
        float x = Xq[r * DD + k];
        sa = fmaf(x, Wa[k * DD + j], sa);
        sb = fmaf(x, Wb[k * DD + j], sb);
    }
    Yab[r * 2 * DD + j] = sa;
    Yab[r * 2 * DD + DD + j] = sb;
}

// Level 1: bin edges by v>>8 into padded bucket regions. 1024 threads: 4 edges
// per thread kept in REGISTERS (short LDS-atomic chains, 7.6 waves/SIMD to hide
// latency); wave-0 shuffle scan (2 barriers, not 16). PROVEN: all sort traffic
// stays in LDS — round-2 showed global scattered atomics cost ~90 B + ~90 cyc
// per edge on this chip (cross-XCD coherence + line write-allocate).
__global__ __launch_bounds__(1024) void bin_kernel(
        const int* __restrict__ u_idx, const int* __restrict__ v_idx,
        int* __restrict__ gcur, unsigned* __restrict__ gbuf, int E) {
    __shared__ unsigned stage[CHUNK];
    __shared__ int hist[NBUCK], off[NBUCK], base[NBUCK], cur[NBUCK];
    int tid = threadIdx.x;
    int e0 = blockIdx.x * CHUNK;
    int n = min(CHUNK, E - e0);
    if (n <= 0) return;

    for (int i = tid; i < NBUCK; i += 1024) hist[i] = 0;
    __syncthreads();

    unsigned p[4];
    int nv = 0;
    int i0 = tid * 4;
    if (i0 + 3 < n) {
        int4 u4 = *(const int4*)(u_idx + e0 + i0);
        int4 v4 = *(const int4*)(v_idx + e0 + i0);
        p[0] = ((unsigned)v4.x << 11) | (unsigned)u4.x;
        p[1] = ((unsigned)v4.y << 11) | (unsigned)u4.y;
        p[2] = ((unsigned)v4.z << 11) | (unsigned)u4.z;
        p[3] = ((unsigned)v4.w << 11) | (unsigned)u4.w;
        nv = 4;
    } else {
        for (int j = 0; j < 4; ++j) {
            if (i0 + j < n) {
                p[j] = ((unsigned)v_idx[e0 + i0 + j] << 11) | (unsigned)u_idx[e0 + i0 + j];
                ++nv;
            }
        }
    }
    for (int j = 0; j < nv; ++j) atomicAdd(&hist[p[j] >> 19], 1);
    __syncthreads();
    if (tid < 64) {   // wave 0: scan 512 buckets, 8 per lane
        int h[8], sum = 0;
#pragma unroll
        for (int j = 0; j < 8; ++j) { h[j] = hist[8 * tid + j]; sum += h[j]; }
        int incl = sum;
#pragma unroll
        for (int d = 1; d < 64; d <<= 1) {
            int y = __shfl_up(incl, d, 64);
            if (tid >= d) incl += y;
        }
        int excl = incl - sum;
#pragma unroll
        for (int j = 0; j < 8; ++j) { off[8 * tid + j] = excl; excl += h[j]; }
    }
    __syncthreads();
    for (int i = tid; i < NBUCK; i += 1024) {
        base[i] = hist[i] ? atomicAdd(&gcur[i], hist[i]) : 0;
        cur[i] = off[i];
    }
    __syncthreads();
    for (int j = 0; j < nv; ++j) {
        int pos = atomicAdd(&cur[p[j] >> 19], 1);
        stage[pos] = p[j];
    }
    __syncthreads();
    for (int i = tid; i < n; i += 1024) {
        unsigned q = stage[i];
        int b = q >> 19;
        int idx = base[b] + (i - off[b]);
        if (idx < BCAP) gbuf[(size_t)b * BCAP + idx] = q;
    }
}

#define DOT4(a, b) fmaf((a).x, (b).x, fmaf((a).y, (b).y, fmaf((a).z, (b).z, (a).w * (b).w)))

// 16-lane all-reduce sum via DPP adds. bound_ctrl=true lets GCNDPPCombine fuse
// mov_dpp+add into a single v_add_f32_dpp. All call sites have full 16-lane
// groups active (edge validity `ok` is group-uniform).
template <int CTRL>
__device__ __forceinline__ float dpp_add(float x) {
    int xi = __builtin_bit_cast(int, x);
    int yi = __builtin_amdgcn_update_dpp(xi, xi, CTRL, 0xF, 0xF, true);
    return x + __builtin_bit_cast(float, yi);
}
__device__ __forceinline__ float red16(float x) {
    x = dpp_add<0xB1>(x);    // quad_perm [1,0,3,2] : xor 1
    x = dpp_add<0x4E>(x);    // quad_perm [2,3,0,1] : xor 2
    x = dpp_add<0x124>(x);   // row_ror:4
    x = dpp_add<0x128>(x);   // row_ror:8
    return x;
}

// v3 row phase: NO sort, NO per-row loop, NO tail gating. Edges streamed
// densely, one edge per 16-lane group; weighted message a*h accumulated into
// per-row LDS accumulators via ds_add_f32 (order-independent sum; stride 65
// spreads rows across banks; same-address collisions rare at 256 rows/block).
// Epilogue: one coalesced divide-and-store per row + consensus/copy for s==0.
__global__ __launch_bounds__(1024, 2) void bucket_kernel(
        const float* __restrict__ Xq,
        const float* __restrict__ Xt,
        const float* __restrict__ Yab,
        const float* __restrict__ ba,
        const float* __restrict__ bb,
        const int* __restrict__ gcur,
        const unsigned* __restrict__ gbuf,
        const int* __restrict__ uc,
        float* __restrict__ outXt) {
    __shared__ float accl[256 * 65];   // [row][65] (64 dims + pad), 66.6 KB
    __shared__ float sacc[256];        // per-row sum of a (==0 iff deg 0)
    int tid = threadIdx.x;
    int b = blockIdx.x;
    int n = min(gcur[b], BCAP);

    for (int i = tid; i < 256 * 65; i += 1024) accl[i] = 0.f;
    if (tid < 256) sacc[tid] = 0.f;
    __syncthreads();

    int lane = tid & 63;
    int w = tid >> 6;          // wave 0..15
    int l16 = lane & 15;
    int g = lane >> 4;         // group 0..3
    float ba0 = ba[0], bb0 = bb[0];
    const unsigned* gb = gbuf + (size_t)b * BCAP;

    int rounds = (n + 63) >> 6;        // block processes 64 edges per round
    for (int t = 0; t < rounds; ++t) {
        int i = (t << 6) + (w << 2) + g;
        bool ok = i < n;               // group-uniform predicate
        unsigned p = gb[ok ? i : 0];
        int v = (int)(p >> 11);
        int u = (int)(p & 0x7FFu);
        const float4* Y = (const float4*)(Yab + (u << 7));
        float4 ya = Y[l16];
        float4 yb = Y[16 + l16];
        float4 xt4 = ((const float4*)(Xt + ((size_t)v << 6)))[l16];
        float4 xq4 = ((const float4*)(Xq + (u << 6)))[l16];
        float pa = DOT4(ya, xt4);
        float pb = DOT4(yb, xt4);
        pa = red16(pa);
        pb = red16(pb);
        float la = pa + ba0;
        float tt = __expf(la);
        float al = la > 0.f ? la : (tt - 1.f);   // elu
        float a = __expf(al);                    // exp(alpha); a >= e^-1 > 0
        float be = __builtin_amdgcn_rcpf(1.f + __expf(-(pb + bb0)));
        float4 ah;                               // a * (xq + be*(xt-xq))
        ah.x = a * fmaf(be, xt4.x - xq4.x, xq4.x);
        ah.y = a * fmaf(be, xt4.y - xq4.y, xq4.y);
        ah.z = a * fmaf(be, xt4.z - xq4.z, xq4.z);
        ah.w = a * fmaf(be, xt4.w - xq4.w, xq4.w);
        if (ok) {
            int r = v & 255;
            float* ap = accl + r * 65 + (l16 << 2);
            atomicAdd(ap + 0, ah.x);
            atomicAdd(ap + 1, ah.y);
            atomicAdd(ap + 2, ah.z);
            atomicAdd(ap + 3, ah.w);
            if (l16 == 0) atomicAdd(&sacc[r], a);
        }
    }
    __syncthreads();

    // epilogue: wave w -> rows w, w+16, ... ; 64 lanes = 64 dims, coalesced.
    for (int r = w; r < 256; r += 16) {
        int v = (b << 8) + r;
        float sv = sacc[r];
        float o;
        if (sv > 0.f) {
            o = accl[r * 65 + lane] * __builtin_amdgcn_rcpf(sv);
        } else if (v >= NT - MM) {     // consensus row: Xq[uc[i]]
            o = Xq[uc[v - (NT - MM)] * DD + lane];
        } else {
            o = Xt[(size_t)v * DD + lane];
        }
        outXt[(size_t)v * DD + lane] = o;
    }
}

extern "C" void kernel_launch(void* const* d_in, const int* in_sizes, int n_in,
                              void* d_out, int out_size, void* d_ws, size_t ws_size,
                              hipStream_t stream) {
    const float* Xq = (const float*)d_in[0];
    const float* Xt = (const float*)d_in[1];
    const float* Wa = (const float*)d_in[2];
    const float* ba = (const float*)d_in[3];
    const float* Wb = (const float*)d_in[4];
    const float* bb = (const float*)d_in[5];
    const int* u_idx = (const int*)d_in[6];
    const int* v_idx = (const int*)d_in[7];
    const int* uc = (const int*)d_in[8];
    const int* vc = (const int*)d_in[9];
    const int E = in_sizes[6];
    (void)vc;

    float* out = (float*)d_out;
    float* outXq = out;                 // NQ*DD
    float* outXt = out + NQ * DD;       // NT*DD

    char* ws = (char*)d_ws;
    float* Yab = (float*)ws;          ws += (size_t)NQ * 2 * DD * sizeof(float);   // 1M
    int* gcur = (int*)ws;             ws += NBUCK * sizeof(int);                   // 2K
    ws = (char*)(((size_t)ws + 255) & ~(size_t)255);
    unsigned* gbuf = (unsigned*)ws;   ws += (size_t)NBUCK * BCAP * sizeof(unsigned);   // 9.4M

    // Output 0 is Xq unchanged.
    hipMemcpyAsync(outXq, Xq, NQ * DD * sizeof(float), hipMemcpyDeviceToDevice, stream);
    hipMemsetAsync(gcur, 0, NBUCK * sizeof(int), stream);

    yq_kernel<<<NQ / 4, 256, 0, stream>>>(Xq, Wa, Wb, Yab);

    int nchunks = (E + CHUNK - 1) / CHUNK;
    bin_kernel<<<nchunks, 1024, 0, stream>>>(u_idx, v_idx, gcur, gbuf, E);

    bucket_kernel<<<NBUCK, 1024, 0, stream>>>(Xq, Xt, Yab, ba, bb, gcur, gbuf,
                                              uc, outXt);
}

// Round 4
// 207.221 us; speedup vs baseline: 3.8398x; 3.8398x over previous
//
#include <hip/hip_runtime.h>

#define NQ 2048
#define NT 131072
#define DD 64
#define MM 1024
#define NBUCK 512          // coarse buckets: v >> 8
#define BCAP 4608          // per-bucket capacity (mean 3906, sigma 62; +11 sigma)
#define CHUNK 4096         // edges per bin block

// LESSONS (measured): r2 global-atomic CSR scatter: 176us, 155MB writes (XCD
// coherence + line write-allocate). r3 per-edge LDS ds_add scatter: 690us,
// VALUBusy 8% (LDS atomic pipe serializes). Edge redistribution must be the
// LDS sort; aggregation must be per-row register accumulation.

typedef __attribute__((ext_vector_type(2))) _Float16 h2;

#if defined(__has_builtin)
#if __has_builtin(__builtin_amdgcn_fdot2)
#define HAVE_FDOT2 1
#endif
#endif

__device__ __forceinline__ float fdot2(h2 a, h2 b, float c) {
#ifdef HAVE_FDOT2
    return __builtin_amdgcn_fdot2(a, b, c, false);
#else
    return fmaf((float)a.x, (float)b.x, fmaf((float)a.y, (float)b.y, c));
#endif
}

// Yab16[u]: 16 granules of 8 halves; granule s (lane l16=s) holds
// {ya[4s..4s+3], yb[4s..4s+3]} -> ONE dwordx4 per lane fetches both score rows.
// Xq16[u]: fp16 copy of Xq row for the h-blend (384B gathered per edge total,
// was 768B fp32 — r0/r1 both pinned at 110us = ~14TB/s scattered-L2 ceiling,
// so bytes/edge is the lever).
__global__ void yq_kernel(const float* __restrict__ Xq,
                          const float* __restrict__ Wa,
                          const float* __restrict__ Wb,
                          _Float16* __restrict__ Yab16,
                          _Float16* __restrict__ Xq16) {
    int r = blockIdx.x * 4 + (threadIdx.x >> 6);
    int j = threadIdx.x & 63;
    float sa = 0.f, sb = 0.f;
#pragma unroll
    for (int k = 0; k < DD; ++k) {
        float x = Xq[r * DD + k];
        sa = fmaf(x, Wa[k * DD + j], sa);
        sb = fmaf(x, Wb[k * DD + j], sb);
    }
    int gbase = r * 128 + (j >> 2) * 8 + (j & 3);
    Yab16[gbase] = (_Float16)sa;
    Yab16[gbase + 4] = (_Float16)sb;
    Xq16[r * DD + j] = (_Float16)Xq[r * DD + j];
}

// Level 1: bin edges by v>>8 into padded bucket regions (all LDS-local).
__global__ __launch_bounds__(1024) void bin_kernel(
        const int* __restrict__ u_idx, const int* __restrict__ v_idx,
        int* __restrict__ gcur, unsigned* __restrict__ gbuf, int E) {
    __shared__ unsigned stage[CHUNK];
    __shared__ int hist[NBUCK], off[NBUCK], base[NBUCK], cur[NBUCK];
    int tid = threadIdx.x;
    int e0 = blockIdx.x * CHUNK;
    int n = min(CHUNK, E - e0);
    if (n <= 0) return;

    for (int i = tid; i < NBUCK; i += 1024) hist[i] = 0;
    __syncthreads();

    unsigned p[4];
    int nv = 0;
    int i0 = tid * 4;
    if (i0 + 3 < n) {
        int4 u4 = *(const int4*)(u_idx + e0 + i0);
        int4 v4 = *(const int4*)(v_idx + e0 + i0);
        p[0] = ((unsigned)v4.x << 11) | (unsigned)u4.x;
        p[1] = ((unsigned)v4.y << 11) | (unsigned)u4.y;
        p[2] = ((unsigned)v4.z << 11) | (unsigned)u4.z;
        p[3] = ((unsigned)v4.w << 11) | (unsigned)u4.w;
        nv = 4;
    } else {
        for (int j = 0; j < 4; ++j) {
            if (i0 + j < n) {
                p[j] = ((unsigned)v_idx[e0 + i0 + j] << 11) | (unsigned)u_idx[e0 + i0 + j];
                ++nv;
            }
        }
    }
    for (int j = 0; j < nv; ++j) atomicAdd(&hist[p[j] >> 19], 1);
    __syncthreads();
    if (tid < 64) {   // wave 0: scan 512 buckets, 8 per lane
        int h[8], sum = 0;
#pragma unroll
        for (int j = 0; j < 8; ++j) { h[j] = hist[8 * tid + j]; sum += h[j]; }
        int incl = sum;
#pragma unroll
        for (int d = 1; d < 64; d <<= 1) {
            int y = __shfl_up(incl, d, 64);
            if (tid >= d) incl += y;
        }
        int excl = incl - sum;
#pragma unroll
        for (int j = 0; j < 8; ++j) { off[8 * tid + j] = excl; excl += h[j]; }
    }
    __syncthreads();
    for (int i = tid; i < NBUCK; i += 1024) {
        base[i] = hist[i] ? atomicAdd(&gcur[i], hist[i]) : 0;
        cur[i] = off[i];
    }
    __syncthreads();
    for (int j = 0; j < nv; ++j) {
        int pos = atomicAdd(&cur[p[j] >> 19], 1);
        stage[pos] = p[j];
    }
    __syncthreads();
    for (int i = tid; i < n; i += 1024) {
        unsigned q = stage[i];
        int b = q >> 19;
        int idx = base[b] + (i - off[b]);
        if (idx < BCAP) gbuf[(size_t)b * BCAP + idx] = q;
    }
}

// 16-lane all-reduce sum via DPP adds (fused v_add_f32_dpp). All call sites
// have full 16-lane groups active (edge validity `ok` is group-uniform).
template <int CTRL>
__device__ __forceinline__ float dpp_add(float x) {
    int xi = __builtin_bit_cast(int, x);
    int yi = __builtin_amdgcn_update_dpp(xi, xi, CTRL, 0xF, 0xF, true);
    return x + __builtin_bit_cast(float, yi);
}
__device__ __forceinline__ float red16(float x) {
    x = dpp_add<0xB1>(x);    // quad_perm [1,0,3,2] : xor 1
    x = dpp_add<0x4E>(x);    // quad_perm [2,3,0,1] : xor 2
    x = dpp_add<0x124>(x);   // row_ror:4
    x = dpp_add<0x128>(x);   // row_ror:8
    return x;
}

// Fused LDS-sort + score + softmax + aggregate + consensus. One block per
// coarse bucket (256 rows). Row phase: one row per wave, 8 edges/iter
// (2 per 16-lane group), wave-uniform deg, tails gated by a=0 selects.
// fp16 packed gathers: 1x dwordx4 (ya+yb) + 1x dwordx2 (xq16) per edge.
__global__ __launch_bounds__(1024, 2) void bucket_kernel(
        const float* __restrict__ Xq,
        const float* __restrict__ Xt,
        const _Float16* __restrict__ Yab16,
        const _Float16* __restrict__ Xq16,
        const float* __restrict__ ba,
        const float* __restrict__ bb,
        const int* __restrict__ gcur,
        const unsigned* __restrict__ gbuf,
        const int* __restrict__ uc,
        float* __restrict__ outXt) {
    __shared__ unsigned short su[BCAP];
    __shared__ int hist[256], cur[256], rstart[257];
    int tid = threadIdx.x;
    int b = blockIdx.x;
    int n = min(gcur[b], BCAP);

    if (tid < 256) hist[tid] = 0;
    __syncthreads();
    for (int i = tid; i < n; i += 1024)
        atomicAdd(&hist[(gbuf[(size_t)b * BCAP + i] >> 11) & 255], 1);
    __syncthreads();
    if (tid < 64) {   // wave 0: scan 256 rows, 4 per lane
        int h0 = hist[4 * tid], h1 = hist[4 * tid + 1];
        int h2_ = hist[4 * tid + 2], h3 = hist[4 * tid + 3];
        int tot = h0 + h1 + h2_ + h3;
        int incl = tot;
#pragma unroll
        for (int d = 1; d < 64; d <<= 1) {
            int y = __shfl_up(incl, d, 64);
            if (tid >= d) incl += y;
        }
        int excl = incl - tot;
        rstart[4 * tid] = excl;             cur[4 * tid] = excl;
        rstart[4 * tid + 1] = excl + h0;    cur[4 * tid + 1] = excl + h0;
        rstart[4 * tid + 2] = excl + h0 + h1;       cur[4 * tid + 2] = excl + h0 + h1;
        rstart[4 * tid + 3] = excl + h0 + h1 + h2_; cur[4 * tid + 3] = excl + h0 + h1 + h2_;
        if (tid == 63) rstart[256] = excl + tot;
    }
    __syncthreads();
    for (int i = tid; i < n; i += 1024) {
        unsigned p = gbuf[(size_t)b * BCAP + i];
        int pos = atomicAdd(&cur[(p >> 11) & 255], 1);
        su[pos] = (unsigned short)(p & 0x7FFu);
    }
    __syncthreads();

    // ---- row phase ----
    int lane = tid & 63;
    int w = tid >> 6;          // wave 0..15
    int l16 = lane & 15;
    int g = lane >> 4;         // group 0..3
    float ba0 = ba[0], bb0 = bb[0];

    for (int r = w; r < 256; r += 16) {
        int v = (b << 8) + r;
        int startr = rstart[r];
        int deg = rstart[r + 1] - startr;   // wave-uniform
        if (deg == 0) {
            if (g == 0) {
                float4 o;
                if (v >= NT - MM) {            // consensus row: Xq[uc[i]] (exact fp32)
                    int u = uc[v - (NT - MM)];
                    o = ((const float4*)(Xq + (size_t)u * DD))[l16];
                } else {
                    o = ((const float4*)(Xt + (size_t)v * DD))[l16];
                }
                ((float4*)(outXt + (size_t)v * DD))[l16] = o;
            }
            continue;
        }
        float4 xt4 = ((const float4*)(Xt + (size_t)v * DD))[l16];
        h2 xt01, xt23;
        xt01.x = (_Float16)xt4.x; xt01.y = (_Float16)xt4.y;
        xt23.x = (_Float16)xt4.z; xt23.y = (_Float16)xt4.w;
        float4 acc = make_float4(0.f, 0.f, 0.f, 0.f);
        float s = 0.f;
        for (int base = 0; base < deg; base += 8) {
            int e0 = base + g;
            int e1 = base + 4 + g;
            bool ok0 = e0 < deg, ok1 = e1 < deg;
            int u0 = (int)su[startr + (ok0 ? e0 : 0)];
            int u1 = (int)su[startr + (ok1 ? e1 : 0)];
            float4 y0 = ((const float4*)(Yab16 + (u0 << 7)))[l16];
            float4 y1 = ((const float4*)(Yab16 + (u1 << 7)))[l16];
            float2 xv0 = ((const float2*)(Xq16 + (u0 << 6)))[l16];
            float2 xv1 = ((const float2*)(Xq16 + (u1 << 6)))[l16];
            float pa0 = fdot2(__builtin_bit_cast(h2, y0.y), xt23,
                       fdot2(__builtin_bit_cast(h2, y0.x), xt01, 0.f));
            float pb0 = fdot2(__builtin_bit_cast(h2, y0.w), xt23,
                       fdot2(__builtin_bit_cast(h2, y0.z), xt01, 0.f));
            float pa1 = fdot2(__builtin_bit_cast(h2, y1.y), xt23,
                       fdot2(__builtin_bit_cast(h2, y1.x), xt01, 0.f));
            float pb1 = fdot2(__builtin_bit_cast(h2, y1.w), xt23,
                       fdot2(__builtin_bit_cast(h2, y1.z), xt01, 0.f));
            pa0 = red16(pa0); pb0 = red16(pb0);
            pa1 = red16(pa1); pb1 = red16(pb1);
            float la0 = pa0 + ba0, la1 = pa1 + ba0;
            float t0 = __expf(la0), t1 = __expf(la1);
            float al0 = la0 > 0.f ? la0 : (t0 - 1.f);
            float al1 = la1 > 0.f ? la1 : (t1 - 1.f);
            float a0 = ok0 ? __expf(al0) : 0.f;   // gate tail edges to zero weight
            float a1 = ok1 ? __expf(al1) : 0.f;
            float be0 = __builtin_amdgcn_rcpf(1.f + __expf(-(pb0 + bb0)));
            float be1 = __builtin_amdgcn_rcpf(1.f + __expf(-(pb1 + bb0)));
            h2 q0a = __builtin_bit_cast(h2, xv0.x), q0b = __builtin_bit_cast(h2, xv0.y);
            h2 q1a = __builtin_bit_cast(h2, xv1.x), q1b = __builtin_bit_cast(h2, xv1.y);
            float x0x = (float)q0a.x, x0y = (float)q0a.y, x0z = (float)q0b.x, x0w = (float)q0b.y;
            float x1x = (float)q1a.x, x1y = (float)q1a.y, x1z = (float)q1b.x, x1w = (float)q1b.y;
            float4 h0v, h1v;
            h0v.x = fmaf(be0, xt4.x - x0x, x0x);
            h0v.y = fmaf(be0, xt4.y - x0y, x0y);
            h0v.z = fmaf(be0, xt4.z - x0z, x0z);
            h0v.w = fmaf(be0, xt4.w - x0w, x0w);
            h1v.x = fmaf(be1, xt4.x - x1x, x1x);
            h1v.y = fmaf(be1, xt4.y - x1y, x1y);
            h1v.z = fmaf(be1, xt4.z - x1z, x1z);
            h1v.w = fmaf(be1, xt4.w - x1w, x1w);
            acc.x = fmaf(a0, h0v.x, fmaf(a1, h1v.x, acc.x));
            acc.y = fmaf(a0, h0v.y, fmaf(a1, h1v.y, acc.y));
            acc.z = fmaf(a0, h0v.z, fmaf(a1, h1v.z, acc.z));
            acc.w = fmaf(a0, h0v.w, fmaf(a1, h1v.w, acc.w));
            s += a0 + a1;
        }
        // combine 4 groups: lanes {l, l+16, l+32, l+48} hold partials of the
        // same feature. Two xor levels give all lanes the totals.
        acc.x += __shfl_xor(acc.x, 16, 64);
        acc.y += __shfl_xor(acc.y, 16, 64);
        acc.z += __shfl_xor(acc.z, 16, 64);
        acc.w += __shfl_xor(acc.w, 16, 64);
        s     += __shfl_xor(s, 16, 64);
        acc.x += __shfl_xor(acc.x, 32, 64);
        acc.y += __shfl_xor(acc.y, 32, 64);
        acc.z += __shfl_xor(acc.z, 32, 64);
        acc.w += __shfl_xor(acc.w, 32, 64);
        s     += __shfl_xor(s, 32, 64);
        if (g == 0) {
            float inv = __builtin_amdgcn_rcpf(s);
            float4 o = make_float4(acc.x * inv, acc.y * inv, acc.z * inv, acc.w * inv);
            ((float4*)(outXt + (size_t)v * DD))[l16] = o;
        }
    }
}

extern "C" void kernel_launch(void* const* d_in, const int* in_sizes, int n_in,
                              void* d_out, int out_size, void* d_ws, size_t ws_size,
                              hipStream_t stream) {
    const float* Xq = (const float*)d_in[0];
    const float* Xt = (const float*)d_in[1];
    const float* Wa = (const float*)d_in[2];
    const float* ba = (const float*)d_in[3];
    const float* Wb = (const float*)d_in[4];
    const float* bb = (const float*)d_in[5];
    const int* u_idx = (const int*)d_in[6];
    const int* v_idx = (const int*)d_in[7];
    const int* uc = (const int*)d_in[8];
    const int* vc = (const int*)d_in[9];
    const int E = in_sizes[6];
    (void)vc;

    float* out = (float*)d_out;
    float* outXq = out;                 // NQ*DD
    float* outXt = out + NQ * DD;       // NT*DD

    char* ws = (char*)d_ws;
    _Float16* Yab16 = (_Float16*)ws;  ws += (size_t)NQ * 2 * DD * sizeof(_Float16);  // 512K
    _Float16* Xq16 = (_Float16*)ws;   ws += (size_t)NQ * DD * sizeof(_Float16);      // 256K
    int* gcur = (int*)ws;             ws += NBUCK * sizeof(int);                     // 2K
    ws = (char*)(((size_t)ws + 255) & ~(size_t)255);
    unsigned* gbuf = (unsigned*)ws;   ws += (size_t)NBUCK * BCAP * sizeof(unsigned); // 9.4M

    // Output 0 is Xq unchanged.
    hipMemcpyAsync(outXq, Xq, NQ * DD * sizeof(float), hipMemcpyDeviceToDevice, stream);
    hipMemsetAsync(gcur, 0, NBUCK * sizeof(int), stream);

    yq_kernel<<<NQ / 4, 256, 0, stream>>>(Xq, Wa, Wb, Yab16, Xq16);

    int nchunks = (E + CHUNK - 1) / CHUNK;
    bin_kernel<<<nchunks, 1024, 0, stream>>>(u_idx, v_idx, gcur, gbuf, E);

    bucket_kernel<<<NBUCK, 1024, 0, stream>>>(Xq, Xt, Yab16, Xq16, ba, bb, gcur, gbuf,
                                              uc, outXt);
}

// Round 5
// 205.825 us; speedup vs baseline: 3.8659x; 1.0068x over previous
//
#include <hip/hip_runtime.h>

#define NQ 2048
#define NT 131072
#define DD 64
#define MM 1024
#define NBUCK 512          // coarse buckets: v >> 8
#define BCAP 4608          // per-bucket capacity (mean 3906, sigma 62; +11 sigma)
#define CHUNK 4096         // edges per bin block

// LESSONS (measured): r2 global-atomic CSR scatter: 176us, 155MB writes (XCD
// coherence + line write-allocate). r3 per-edge LDS ds_add scatter: 690us,
// VALUBusy 8% (LDS atomic pipe serializes). r4 fp16 halved gathered bytes,
// bucket only -13% => VALU-issue bound, not L2-BW bound. Edge redistribution
// must be the LDS sort; aggregation must be per-row register accumulation.

typedef __attribute__((ext_vector_type(2))) _Float16 h2;

#if defined(__has_builtin)
#if __has_builtin(__builtin_amdgcn_fdot2)
#define HAVE_FDOT2 1
#endif
#endif

__device__ __forceinline__ float fdot2(h2 a, h2 b, float c) {
#ifdef HAVE_FDOT2
    return __builtin_amdgcn_fdot2(a, b, c, false);
#else
    return fmaf((float)a.x, (float)b.x, fmaf((float)a.y, (float)b.y, c));
#endif
}

// Fused bin + Yab/Xq16 precompute + outXq copy. Blocks [0, nchunks) bin edges
// by v>>8 into padded bucket regions (all LDS-local, structure proven r0-r4).
// Blocks [nchunks, nchunks+128) compute Yab16/Xq16 (16 rows per 1024-thr block)
// and write outXq — independent work that previously ran as 2 serial launches.
__global__ __launch_bounds__(1024) void bin_yq_kernel(
        const int* __restrict__ u_idx, const int* __restrict__ v_idx,
        int* __restrict__ gcur, unsigned* __restrict__ gbuf,
        const float* __restrict__ Xq,
        const float* __restrict__ Wa, const float* __restrict__ Wb,
        _Float16* __restrict__ Yab16, _Float16* __restrict__ Xq16,
        float* __restrict__ outXq, int E) {
    __shared__ unsigned stage[CHUNK];
    __shared__ int hist[NBUCK], off[NBUCK], base[NBUCK], cur[NBUCK];
    int tid = threadIdx.x;
    int nchunks = (E + CHUNK - 1) / CHUNK;

    if (blockIdx.x >= nchunks) {        // ---- yq role ----
        int r = (blockIdx.x - nchunks) * 16 + (tid >> 6);
        int j = tid & 63;
        float sa = 0.f, sb = 0.f;
#pragma unroll
        for (int k = 0; k < DD; ++k) {
            float x = Xq[r * DD + k];   // wave-uniform address -> scalar load
            sa = fmaf(x, Wa[k * DD + j], sa);
            sb = fmaf(x, Wb[k * DD + j], sb);
        }
        // Yab16[u]: granule s holds {ya[4s..4s+3], yb[4s..4s+3]} -> one dwordx4
        // per lane fetches both score rows in bucket_kernel.
        int gbase = r * 128 + (j >> 2) * 8 + (j & 3);
        Yab16[gbase] = (_Float16)sa;
        Yab16[gbase + 4] = (_Float16)sb;
        float xj = Xq[r * DD + j];
        Xq16[r * DD + j] = (_Float16)xj;
        outXq[r * DD + j] = xj;         // replaces the outXq memcpy dispatch
        return;
    }

    // ---- bin role ----
    int e0 = blockIdx.x * CHUNK;
    int n = min(CHUNK, E - e0);
    if (n <= 0) return;

    for (int i = tid; i < NBUCK; i += 1024) hist[i] = 0;
    __syncthreads();

    unsigned p[4];
    int nv = 0;
    int i0 = tid * 4;
    if (i0 + 3 < n) {
        int4 u4 = *(const int4*)(u_idx + e0 + i0);
        int4 v4 = *(const int4*)(v_idx + e0 + i0);
        p[0] = ((unsigned)v4.x << 11) | (unsigned)u4.x;
        p[1] = ((unsigned)v4.y << 11) | (unsigned)u4.y;
        p[2] = ((unsigned)v4.z << 11) | (unsigned)u4.z;
        p[3] = ((unsigned)v4.w << 11) | (unsigned)u4.w;
        nv = 4;
    } else {
        for (int j = 0; j < 4; ++j) {
            if (i0 + j < n) {
                p[j] = ((unsigned)v_idx[e0 + i0 + j] << 11) | (unsigned)u_idx[e0 + i0 + j];
                ++nv;
            }
        }
    }
    for (int j = 0; j < nv; ++j) atomicAdd(&hist[p[j] >> 19], 1);
    __syncthreads();
    if (tid < 64) {   // wave 0: scan 512 buckets, 8 per lane
        int h[8], sum = 0;
#pragma unroll
        for (int j = 0; j < 8; ++j) { h[j] = hist[8 * tid + j]; sum += h[j]; }
        int incl = sum;
#pragma unroll
        for (int d = 1; d < 64; d <<= 1) {
            int y = __shfl_up(incl, d, 64);
            if (tid >= d) incl += y;
        }
        int excl = incl - sum;
#pragma unroll
        for (int j = 0; j < 8; ++j) { off[8 * tid + j] = excl; excl += h[j]; }
    }
    __syncthreads();
    for (int i = tid; i < NBUCK; i += 1024) {
        base[i] = hist[i] ? atomicAdd(&gcur[i], hist[i]) : 0;
        cur[i] = off[i];
    }
    __syncthreads();
    for (int j = 0; j < nv; ++j) {
        int pos = atomicAdd(&cur[p[j] >> 19], 1);
        stage[pos] = p[j];
    }
    __syncthreads();
    for (int i = tid; i < n; i += 1024) {
        unsigned q = stage[i];
        int b = q >> 19;
        int idx = base[b] + (i - off[b]);
        if (idx < BCAP) gbuf[(size_t)b * BCAP + idx] = q;
    }
}

// 16-lane all-reduce sum via DPP adds (fused v_add_f32_dpp). All call sites
// have full 16-lane groups active (edge validity `ok` is group-uniform).
template <int CTRL>
__device__ __forceinline__ float dpp_add(float x) {
    int xi = __builtin_bit_cast(int, x);
    int yi = __builtin_amdgcn_update_dpp(xi, xi, CTRL, 0xF, 0xF, true);
    return x + __builtin_bit_cast(float, yi);
}
__device__ __forceinline__ float red16(float x) {
    x = dpp_add<0xB1>(x);    // quad_perm [1,0,3,2] : xor 1
    x = dpp_add<0x4E>(x);    // quad_perm [2,3,0,1] : xor 2
    x = dpp_add<0x124>(x);   // row_ror:4
    x = dpp_add<0x128>(x);   // row_ror:8
    return x;
}

// Fused LDS-sort + score + softmax + aggregate + consensus. One block per
// coarse bucket (256 rows). Row phase: one row per wave, 8 edges/iter
// (2 per 16-lane group), wave-uniform deg, tails gated by a=0 selects.
// v5: beta-blend hoisted out of edge loop (acc += (a-a*be)*xq; xt-term is
// (sum a*be)*xt added once per row) + fma_mix f16 accumulate (no cvts).
__global__ __launch_bounds__(1024, 2) void bucket_kernel(
        const float* __restrict__ Xq,
        const float* __restrict__ Xt,
        const _Float16* __restrict__ Yab16,
        const _Float16* __restrict__ Xq16,
        const float* __restrict__ ba,
        const float* __restrict__ bb,
        const int* __restrict__ gcur,
        const unsigned* __restrict__ gbuf,
        const int* __restrict__ uc,
        float* __restrict__ outXt) {
    __shared__ unsigned short su[BCAP];
    __shared__ int hist[256], cur[256], rstart[257];
    int tid = threadIdx.x;
    int b = blockIdx.x;
    int n = min(gcur[b], BCAP);

    if (tid < 256) hist[tid] = 0;
    __syncthreads();
    for (int i = tid; i < n; i += 1024)
        atomicAdd(&hist[(gbuf[(size_t)b * BCAP + i] >> 11) & 255], 1);
    __syncthreads();
    if (tid < 64) {   // wave 0: scan 256 rows, 4 per lane
        int h0 = hist[4 * tid], h1 = hist[4 * tid + 1];
        int h2_ = hist[4 * tid + 2], h3 = hist[4 * tid + 3];
        int tot = h0 + h1 + h2_ + h3;
        int incl = tot;
#pragma unroll
        for (int d = 1; d < 64; d <<= 1) {
            int y = __shfl_up(incl, d, 64);
            if (tid >= d) incl += y;
        }
        int excl = incl - tot;
        rstart[4 * tid] = excl;             cur[4 * tid] = excl;
        rstart[4 * tid + 1] = excl + h0;    cur[4 * tid + 1] = excl + h0;
        rstart[4 * tid + 2] = excl + h0 + h1;       cur[4 * tid + 2] = excl + h0 + h1;
        rstart[4 * tid + 3] = excl + h0 + h1 + h2_; cur[4 * tid + 3] = excl + h0 + h1 + h2_;
        if (tid == 63) rstart[256] = excl + tot;
    }
    __syncthreads();
    for (int i = tid; i < n; i += 1024) {
        unsigned p = gbuf[(size_t)b * BCAP + i];
        int pos = atomicAdd(&cur[(p >> 11) & 255], 1);
        su[pos] = (unsigned short)(p & 0x7FFu);
    }
    __syncthreads();

    // ---- row phase ----
    int lane = tid & 63;
    int w = tid >> 6;          // wave 0..15
    int l16 = lane & 15;
    int g = lane >> 4;         // group 0..3
    float ba0 = ba[0], bb0 = bb[0];

    for (int r = w; r < 256; r += 16) {
        int v = (b << 8) + r;
        int startr = rstart[r];
        int deg = rstart[r + 1] - startr;   // wave-uniform
        if (deg == 0) {
            if (g == 0) {
                float4 o;
                if (v >= NT - MM) {            // consensus row: Xq[uc[i]] (exact fp32)
                    int u = uc[v - (NT - MM)];
                    o = ((const float4*)(Xq + (size_t)u * DD))[l16];
                } else {
                    o = ((const float4*)(Xt + (size_t)v * DD))[l16];
                }
                ((float4*)(outXt + (size_t)v * DD))[l16] = o;
            }
            continue;
        }
        float4 xt4 = ((const float4*)(Xt + (size_t)v * DD))[l16];
        h2 xt01, xt23;
        xt01.x = (_Float16)xt4.x; xt01.y = (_Float16)xt4.y;
        xt23.x = (_Float16)xt4.z; xt23.y = (_Float16)xt4.w;
        float4 acc = make_float4(0.f, 0.f, 0.f, 0.f);
        float s = 0.f;     // sum a        (softmax denominator)
        float s2 = 0.f;    // sum a*beta   (hoisted xt coefficient)
        for (int base = 0; base < deg; base += 8) {
            int e0 = base + g;
            int e1 = base + 4 + g;
            bool ok0 = e0 < deg, ok1 = e1 < deg;
            int u0 = (int)su[startr + (ok0 ? e0 : 0)];
            int u1 = (int)su[startr + (ok1 ? e1 : 0)];
            float4 y0 = ((const float4*)(Yab16 + (u0 << 7)))[l16];
            float4 y1 = ((const float4*)(Yab16 + (u1 << 7)))[l16];
            float2 xv0 = ((const float2*)(Xq16 + (u0 << 6)))[l16];
            float2 xv1 = ((const float2*)(Xq16 + (u1 << 6)))[l16];
            float pa0 = fdot2(__builtin_bit_cast(h2, y0.y), xt23,
                       fdot2(__builtin_bit_cast(h2, y0.x), xt01, 0.f));
            float pb0 = fdot2(__builtin_bit_cast(h2, y0.w), xt23,
                       fdot2(__builtin_bit_cast(h2, y0.z), xt01, 0.f));
            float pa1 = fdot2(__builtin_bit_cast(h2, y1.y), xt23,
                       fdot2(__builtin_bit_cast(h2, y1.x), xt01, 0.f));
            float pb1 = fdot2(__builtin_bit_cast(h2, y1.w), xt23,
                       fdot2(__builtin_bit_cast(h2, y1.z), xt01, 0.f));
            pa0 = red16(pa0); pb0 = red16(pb0);
            pa1 = red16(pa1); pb1 = red16(pb1);
            float la0 = pa0 + ba0, la1 = pa1 + ba0;
            float t0 = __expf(la0), t1 = __expf(la1);
            float al0 = la0 > 0.f ? la0 : (t0 - 1.f);
            float al1 = la1 > 0.f ? la1 : (t1 - 1.f);
            float a0 = ok0 ? __expf(al0) : 0.f;   // gate tail edges to zero weight
            float a1 = ok1 ? __expf(al1) : 0.f;
            float be0 = __builtin_amdgcn_rcpf(1.f + __expf(-(pb0 + bb0)));
            float be1 = __builtin_amdgcn_rcpf(1.f + __expf(-(pb1 + bb0)));
            float c20 = a0 * be0, c21 = a1 * be1;   // a*beta  (xt coeff)
            float c10 = a0 - c20, c11 = a1 - c21;   // a*(1-beta) (xq coeff)
            h2 q0a = __builtin_bit_cast(h2, xv0.x), q0b = __builtin_bit_cast(h2, xv0.y);
            h2 q1a = __builtin_bit_cast(h2, xv1.x), q1b = __builtin_bit_cast(h2, xv1.y);
            // v_fma_mix_f32: f16 source * f32 coeff + f32 acc, no cvt insts
            acc.x = fmaf((float)q0a.x, c10, acc.x);
            acc.y = fmaf((float)q0a.y, c10, acc.y);
            acc.z = fmaf((float)q0b.x, c10, acc.z);
            acc.w = fmaf((float)q0b.y, c10, acc.w);
            acc.x = fmaf((float)q1a.x, c11, acc.x);
            acc.y = fmaf((float)q1a.y, c11, acc.y);
            acc.z = fmaf((float)q1b.x, c11, acc.z);
            acc.w = fmaf((float)q1b.y, c11, acc.w);
            s += a0 + a1;
            s2 += c20 + c21;
        }
        // combine 4 groups: lanes {l, l+16, l+32, l+48} hold partials of the
        // same feature. Two xor levels give all lanes the totals.
        acc.x += __shfl_xor(acc.x, 16, 64);
        acc.y += __shfl_xor(acc.y, 16, 64);
        acc.z += __shfl_xor(acc.z, 16, 64);
        acc.w += __shfl_xor(acc.w, 16, 64);
        s     += __shfl_xor(s, 16, 64);
        s2    += __shfl_xor(s2, 16, 64);
        acc.x += __shfl_xor(acc.x, 32, 64);
        acc.y += __shfl_xor(acc.y, 32, 64);
        acc.z += __shfl_xor(acc.z, 32, 64);
        acc.w += __shfl_xor(acc.w, 32, 64);
        s     += __shfl_xor(s, 32, 64);
        s2    += __shfl_xor(s2, 32, 64);
        if (g == 0) {
            float inv = __builtin_amdgcn_rcpf(s);
            float4 o;
            o.x = fmaf(s2, xt4.x, acc.x) * inv;
            o.y = fmaf(s2, xt4.y, acc.y) * inv;
            o.z = fmaf(s2, xt4.z, acc.z) * inv;
            o.w = fmaf(s2, xt4.w, acc.w) * inv;
            ((float4*)(outXt + (size_t)v * DD))[l16] = o;
        }
    }
}

extern "C" void kernel_launch(void* const* d_in, const int* in_sizes, int n_in,
                              void* d_out, int out_size, void* d_ws, size_t ws_size,
                              hipStream_t stream) {
    const float* Xq = (const float*)d_in[0];
    const float* Xt = (const float*)d_in[1];
    const float* Wa = (const float*)d_in[2];
    const float* ba = (const float*)d_in[3];
    const float* Wb = (const float*)d_in[4];
    const float* bb = (const float*)d_in[5];
    const int* u_idx = (const int*)d_in[6];
    const int* v_idx = (const int*)d_in[7];
    const int* uc = (const int*)d_in[8];
    const int* vc = (const int*)d_in[9];
    const int E = in_sizes[6];
    (void)vc;

    float* out = (float*)d_out;
    float* outXq = out;                 // NQ*DD
    float* outXt = out + NQ * DD;       // NT*DD

    char* ws = (char*)d_ws;
    _Float16* Yab16 = (_Float16*)ws;  ws += (size_t)NQ * 2 * DD * sizeof(_Float16);  // 512K
    _Float16* Xq16 = (_Float16*)ws;   ws += (size_t)NQ * DD * sizeof(_Float16);      // 256K
    int* gcur = (int*)ws;             ws += NBUCK * sizeof(int);                     // 2K
    ws = (char*)(((size_t)ws + 255) & ~(size_t)255);
    unsigned* gbuf = (unsigned*)ws;   ws += (size_t)NBUCK * BCAP * sizeof(unsigned); // 9.4M

    hipMemsetAsync(gcur, 0, NBUCK * sizeof(int), stream);

    int nchunks = (E + CHUNK - 1) / CHUNK;
    bin_yq_kernel<<<nchunks + NQ / 16, 1024, 0, stream>>>(
        u_idx, v_idx, gcur, gbuf, Xq, Wa, Wb, Yab16, Xq16, outXq, E);

    bucket_kernel<<<NBUCK, 1024, 0, stream>>>(Xq, Xt, Yab16, Xq16, ba, bb, gcur, gbuf,
                                              uc, outXt);
}